// Round 10
// baseline (538.416 us; speedup 1.0000x reference)
//
#include <hip/hip_runtime.h>
#include <hip/hip_bf16.h>

typedef int v4i __attribute__((ext_vector_type(4)));

#define M_DIM 16384
#define N_DIM 4096
#define K_DIM 4096
#define BM 256
#define BN 256
#define BKB 128                 // K-bytes per tile
#define NT (K_DIM / BKB)        // 32 K-tiles

#define QBLK 2048               // quant-x blocks in fused prep
#define PBLK 512                // pack-w blocks in fused prep

// ---- fused pre-pass: grid-partitioned quant(x) || pack(w) (r9 form) ----
__global__ void prep_kernel(const float4* __restrict__ x, int4* __restrict__ qx, int n16x,
                            const int4* __restrict__ w, int4* __restrict__ qw, int n16w,
                            const float* __restrict__ act_scale) {
  if (blockIdx.x < QBLK) {
    const float s = fmaxf(act_scale[0], 1e-5f);
    const float inv_s = 1.0f / s;
#define PKQ(v) (( (int)fminf(fmaxf(rintf((v).x * inv_s), -127.f), 127.f) & 0xff)        | \
               (((int)fminf(fmaxf(rintf((v).y * inv_s), -127.f), 127.f) & 0xff) << 8)  | \
               (((int)fminf(fmaxf(rintf((v).z * inv_s), -127.f), 127.f) & 0xff) << 16) | \
               (((int)fminf(fmaxf(rintf((v).w * inv_s), -127.f), 127.f) & 0xff) << 24))
    int i = blockIdx.x * blockDim.x + threadIdx.x;
    const int stride = QBLK * blockDim.x;
    for (; i < n16x; i += stride) {
      const float4* xp = x + (size_t)i * 4;
      float4 v0 = xp[0], v1 = xp[1], v2 = xp[2], v3 = xp[3];
      int4 o;
      o.x = PKQ(v0); o.y = PKQ(v1); o.z = PKQ(v2); o.w = PKQ(v3);
      qx[i] = o;
    }
  } else {
#define PKW(v) ((((v).x - 1) & 0xff) | ((((v).y - 1) & 0xff) << 8) | \
                ((((v).z - 1) & 0xff) << 16) | ((((v).w - 1) & 0xff) << 24))
    int i = (blockIdx.x - QBLK) * blockDim.x + threadIdx.x;
    const int stride = PBLK * blockDim.x;
    for (; i < n16w; i += stride) {
      const int4* wp = w + (size_t)i * 4;
      int4 v0 = wp[0], v1 = wp[1], v2 = wp[2], v3 = wp[3];
      int4 o;
      o.x = PKW(v0); o.y = PKW(v1); o.z = PKW(v2); o.w = PKW(v3);
      qw[i] = o;
    }
  }
}

// ---- i8 GEMM, r10: SAME 256^2 block tile, 16 WAVES (1024 thr), 64x64
// wave-tile -> 4 waves/SIMD (was 2). Mechanism: the residual cost is the
// post-barrier read-burst->MFMA serialization per wave; doubling wave count
// (each with half-size read sets) lets early-finishing waves' MFMAs overlap
// the read-burst tail. FETCH cannot move (r7 guard): same grid, same block
// tile, same staging bytes. Register budget halves: acc 64 AGPR + ~60 VGPR
// <= 128/wave (required for the 16-wave group to be resident). LDS reads
// 192->256 instr/tile (+33%), writes stay 64, bank profile identical (same
// XOR swizzle; the new 2-way row alias on writes is free per m136). All
// verified mappings inherited: stored layout, XOR store/read swizzle,
// 16x16x64 fragment + C/D maps, XCD swizzle (nwg=1024), TILE_LAST trim (r9).
__global__ __launch_bounds__(1024, 1) void bitlinear_gemm(
    const signed char* __restrict__ A,   // [M][K] i8
    const signed char* __restrict__ B,   // [N][K] i8
    const float* __restrict__ bias,
    const float* __restrict__ alpha_p,
    const float* __restrict__ act_scale_p,
    float* __restrict__ out) {
  __shared__ __align__(16) signed char As[2][BM * BKB];   // 2 x 32 KiB
  __shared__ __align__(16) signed char Bs[2][BN * BKB];   // 2 x 32 KiB

  const int t = threadIdx.x;
  const int lane = t & 63, wid = t >> 6;       // 16 waves
  const int wm = wid >> 2, wn = wid & 3;       // 4M x 4N waves, 64x64 each
  const int l15 = lane & 15, l4 = lane >> 4;

  // XCD-aware bijective swizzle (nwg=1024, divisible by 8)
  const int nwg = (M_DIM / BM) * (N_DIM / BN);
  const int wg = (blockIdx.x & 7) * (nwg >> 3) + (blockIdx.x >> 3);
  const int bm = wg / (N_DIM / BN);
  const int bn = wg % (N_DIM / BN);

  // ---- reg-staging addressing: LINEAR global loads, SWIZZLED ds_write ----
  // 1024 threads: row = t>>2 (0..255), chunks (t&3) and (t&3)+4 (16B each).
  const signed char* aGl = A + ((size_t)(bm * BM + (t >> 2))) * K_DIM + (t & 3) * 16;
  const signed char* bGl = B + ((size_t)(bn * BN + (t >> 2))) * K_DIM + (t & 3) * 16;
  // LDS write offsets: row*128 + ((chunk ^ (row&7))*16), chunk = (t&3)+4u
  const int wr0 = (t >> 2) * 128 + ((((t & 3) + 0) ^ ((t >> 2) & 7)) * 16);
  const int wr1 = (t >> 2) * 128 + ((((t & 3) + 4) ^ ((t >> 2) & 7)) * 16);

  v4i sA[2], sB[2];   // staging registers (one tile in flight, 32B/thread)

#define GL_A(u, P) sA[u] = *(const v4i*)((P) + (u) * 64)
#define GL_B(u, P) sB[u] = *(const v4i*)((P) + (u) * 64)
#define WR_A(BUF) { *(v4i*)&As[BUF][wr0] = sA[0]; *(v4i*)&As[BUF][wr1] = sA[1]; }
#define WR_B(BUF) { *(v4i*)&Bs[BUF][wr0] = sB[0]; *(v4i*)&Bs[BUF][wr1] = sB[1]; }

  // ---- fragment read addressing (zero-conflict XOR layout, unchanged) ----
  const int l7 = l15 & 7;
  const int soK0 = ((0 + l4) ^ l7) * 16;   // kstep 0 chunk
  const int soK1 = ((4 + l4) ^ l7) * 16;   // kstep 1 chunk
  const int aRd = (wm * 64 + l15) * BKB;
  const int bRd = (wn * 64 + l15) * BKB;

  v4i acc[4][4] = {};       // [msub][nsub] 16x16 tiles: 64 AGPR
  v4i bF[4][2], aF[2];

#define LOAD_B(buf) \
  { _Pragma("unroll") for (int nc = 0; nc < 4; ++nc) { \
      bF[nc][0] = *(const v4i*)&Bs[buf][bRd + nc * 2048 + soK0]; \
      bF[nc][1] = *(const v4i*)&Bs[buf][bRd + nc * 2048 + soK1]; } }

#define LOAD_A(buf, m) \
  aF[0] = *(const v4i*)&As[buf][aRd + (m) * 2048 + soK0]; \
  aF[1] = *(const v4i*)&As[buf][aRd + (m) * 2048 + soK1];

#define MFMA_M(m) \
  { _Pragma("unroll") for (int nc = 0; nc < 4; ++nc) { \
      acc[m][nc] = __builtin_amdgcn_mfma_i32_16x16x64_i8(aF[0], bF[nc][0], acc[m][nc], 0, 0, 0); \
      acc[m][nc] = __builtin_amdgcn_mfma_i32_16x16x64_i8(aF[1], bF[nc][1], acc[m][nc], 0, 0, 0); } }

#define BAR __builtin_amdgcn_s_barrier()

  // One K-tile: 4 m-subtiles in program order, no intra-tile barriers;
  // single lgkmcnt(0)+barrier at the buffer flip (champion schedule).
#define TILE_BODY(BUF, PA, PB) do { \
    LOAD_B(BUF); LOAD_A(BUF, 0); \
    GL_B(0, PB); \
    __builtin_amdgcn_s_setprio(1); MFMA_M(0); __builtin_amdgcn_s_setprio(0); \
    LOAD_A(BUF, 1); \
    GL_B(1, PB); \
    __builtin_amdgcn_s_setprio(1); MFMA_M(1); __builtin_amdgcn_s_setprio(0); \
    LOAD_A(BUF, 2); \
    GL_A(0, PA); GL_A(1, PA); \
    __builtin_amdgcn_s_setprio(1); MFMA_M(2); __builtin_amdgcn_s_setprio(0); \
    WR_B(BUF^1); \
    LOAD_A(BUF, 3); \
    __builtin_amdgcn_s_setprio(1); MFMA_M(3); __builtin_amdgcn_s_setprio(0); \
    WR_A(BUF^1); \
    asm volatile("s_waitcnt lgkmcnt(0)" ::: "memory"); \
    BAR; \
  } while (0)

  // Final tile: no staging, no flip drain/barrier (r9 trim).
#define TILE_LAST(BUF) do { \
    LOAD_B(BUF); LOAD_A(BUF, 0); \
    __builtin_amdgcn_s_setprio(1); MFMA_M(0); __builtin_amdgcn_s_setprio(0); \
    LOAD_A(BUF, 1); \
    __builtin_amdgcn_s_setprio(1); MFMA_M(1); __builtin_amdgcn_s_setprio(0); \
    LOAD_A(BUF, 2); \
    __builtin_amdgcn_s_setprio(1); MFMA_M(2); __builtin_amdgcn_s_setprio(0); \
    LOAD_A(BUF, 3); \
    __builtin_amdgcn_s_setprio(1); MFMA_M(3); __builtin_amdgcn_s_setprio(0); \
  } while (0)

  // ---- prologue: load + write tile 0 ----
  GL_B(0, bGl); GL_B(1, bGl);
  GL_A(0, aGl); GL_A(1, aGl);
  asm volatile("s_waitcnt vmcnt(0)" ::: "memory");
  WR_B(0); WR_A(0);
  asm volatile("s_waitcnt lgkmcnt(0)" ::: "memory");
  BAR;
  __builtin_amdgcn_sched_barrier(0);

  // ---- main loop: 2 K-tiles per iteration, compile-time buffer selection ----
  const signed char* aGk = aGl;
  const signed char* bGk = bGl;
  for (int it = 0; it < NT / 2 - 1; ++it) {
    TILE_BODY(0, aGk + BKB,     bGk + BKB);       // tile 2it,   load 2it+1
    TILE_BODY(1, aGk + 2 * BKB, bGk + 2 * BKB);   // tile 2it+1, load 2it+2
    aGk += 2 * BKB; bGk += 2 * BKB;
  }
  TILE_BODY(0, aGk + BKB, bGk + BKB);             // tile 30, load 31
  TILE_LAST(1);                                   // tile 31, no staging

  // ---- epilogue: out = acc * (clamped_act_scale * alpha) + bias ----
  const float sA_ = fmaxf(act_scale_p[0], 1e-5f) * alpha_p[0];
  const int gn0 = bn * BN + wn * 64 + l15;
  const int gm0 = bm * BM + wm * 64 + l4 * 4;
#pragma unroll
  for (int nc = 0; nc < 4; ++nc) {
    const float bv = bias[gn0 + nc * 16];
#pragma unroll
    for (int mr = 0; mr < 4; ++mr) {
#pragma unroll
      for (int r = 0; r < 4; ++r) {
        const int gm = gm0 + mr * 16 + r;          // C/D: col=lane&15, row=(lane>>4)*4+reg
        out[(size_t)gm * N_DIM + gn0 + nc * 16] = (float)acc[mr][nc][r] * sA_ + bv;
      }
    }
  }
}

extern "C" void kernel_launch(void* const* d_in, const int* in_sizes, int n_in,
                              void* d_out, int out_size, void* d_ws, size_t ws_size,
                              hipStream_t stream) {
  const float* x      = (const float*)d_in[0];
  const int*   pw     = (const int*)d_in[1];
  const float* alpha  = (const float*)d_in[2];
  const float* act_sc = (const float*)d_in[3];
  const float* bias   = (const float*)d_in[4];
  float* out = (float*)d_out;

  signed char* x8 = (signed char*)d_ws;                          // 64 MiB
  signed char* w8 = (signed char*)d_ws + (size_t)M_DIM * K_DIM;  // 16 MiB

  prep_kernel<<<QBLK + PBLK, 256, 0, stream>>>(
      (const float4*)x, (int4*)x8, M_DIM * K_DIM / 16,
      (const int4*)pw, (int4*)w8, N_DIM * K_DIM / 16, act_sc);

  dim3 grid((M_DIM / BM) * (N_DIM / BN));   // 1024 blocks, 1-D for XCD swizzle
  bitlinear_gemm<<<grid, 1024, 0, stream>>>(x8, w8, bias, alpha, act_sc, out);
}

// Round 11
// 362.901 us; speedup vs baseline: 1.4836x; 1.4836x over previous
//
#include <hip/hip_runtime.h>
#include <hip/hip_bf16.h>

typedef int v4i __attribute__((ext_vector_type(4)));

#define M_DIM 16384
#define N_DIM 4096
#define K_DIM 4096
#define BM 256
#define BN 256
#define BKB 128                 // K-bytes per tile
#define NT (K_DIM / BKB)        // 32 K-tiles

#define QBLK 2048               // quant-x blocks in fused prep
#define PBLK 512                // pack-w blocks in fused prep

// ---- fused pre-pass: grid-partitioned quant(x) || pack(w).
// r5: reciprocal-multiply (div was VALU-bound). r6: fused single launch.
// r9: 4 vectors/lane -> one int4 (16B) store.
__global__ void prep_kernel(const float4* __restrict__ x, int4* __restrict__ qx, int n16x,
                            const int4* __restrict__ w, int4* __restrict__ qw, int n16w,
                            const float* __restrict__ act_scale) {
  if (blockIdx.x < QBLK) {
    const float s = fmaxf(act_scale[0], 1e-5f);
    const float inv_s = 1.0f / s;
#define PKQ(v) (( (int)fminf(fmaxf(rintf((v).x * inv_s), -127.f), 127.f) & 0xff)        | \
               (((int)fminf(fmaxf(rintf((v).y * inv_s), -127.f), 127.f) & 0xff) << 8)  | \
               (((int)fminf(fmaxf(rintf((v).z * inv_s), -127.f), 127.f) & 0xff) << 16) | \
               (((int)fminf(fmaxf(rintf((v).w * inv_s), -127.f), 127.f) & 0xff) << 24))
    int i = blockIdx.x * blockDim.x + threadIdx.x;
    const int stride = QBLK * blockDim.x;
    for (; i < n16x; i += stride) {
      const float4* xp = x + (size_t)i * 4;
      float4 v0 = xp[0], v1 = xp[1], v2 = xp[2], v3 = xp[3];
      int4 o;
      o.x = PKQ(v0); o.y = PKQ(v1); o.z = PKQ(v2); o.w = PKQ(v3);
      qx[i] = o;
    }
  } else {
#define PKW(v) ((((v).x - 1) & 0xff) | ((((v).y - 1) & 0xff) << 8) | \
                ((((v).z - 1) & 0xff) << 16) | ((((v).w - 1) & 0xff) << 24))
    int i = (blockIdx.x - QBLK) * blockDim.x + threadIdx.x;
    const int stride = PBLK * blockDim.x;
    for (; i < n16w; i += stride) {
      const int4* wp = w + (size_t)i * 4;
      int4 v0 = wp[0], v1 = wp[1], v2 = wp[2], v3 = wp[3];
      int4 o;
      o.x = PKW(v0); o.y = PKW(v1); o.z = PKW(v2); o.w = PKW(v3);
      qw[i] = o;
    }
  }
}

// ---- i8 GEMM: r9 CHAMPION restored (272us GEMM, 0 conflicts, 362.4 total).
// Final structure-space ledger (GEMM dispatch us):
//   reg-staging+barrier-free 256^2 (this)  272   <- champion
//   reg-staging+4-phase ladder             305
//   global_load_lds DMA + barrier-free     315   (waitcnt pass aliases DMA vs all LDS)
//   DMA + ladder                           312
//   128^2 tile (2 blk/CU)                  390   (FETCH 3x: reuse loss > overlap)
//   32x32x32 MFMA                          297   (2.5e7 bank conflicts under v16i pressure)
//   A-direct-from-L2                       584   (in-order vmcnt entanglement + L2 BW)
//   16-wave 256^2 (4 w/SIMD)               444   (staging-coset write conflicts,
//                                                 2.4x WRITE amplification, MfmaUtil 26)
// Champion mechanisms, each verified load-bearing: compiler-counted vmcnt on
// reg-staging GLs; 128x64 wave-tile = per-output LDS-read optimum; single
// lgkmcnt(0)+barrier per K-tile; zero-conflict XOR LDS layout (8 lanes/row
// staging covers all 8 chunks/row); bijective XCD swizzle; staging-free
// TILE_LAST. Plateau at 46% of i8 MFMA ubench: latency/convoy-bound at
// 1 block/CU (register wall), all measured structural exits regress.
__global__ __launch_bounds__(512, 2) void bitlinear_gemm(
    const signed char* __restrict__ A,   // [M][K] i8
    const signed char* __restrict__ B,   // [N][K] i8
    const float* __restrict__ bias,
    const float* __restrict__ alpha_p,
    const float* __restrict__ act_scale_p,
    float* __restrict__ out) {
  __shared__ __align__(16) signed char As[2][BM * BKB];   // 2 x 32 KiB
  __shared__ __align__(16) signed char Bs[2][BN * BKB];   // 2 x 32 KiB

  const int t = threadIdx.x;
  const int lane = t & 63, wid = t >> 6;
  const int wm = wid >> 2, wn = wid & 3;       // 2M x 4N waves
  const int l15 = lane & 15, l4 = lane >> 4;

  // XCD-aware bijective swizzle (nwg=1024, divisible by 8)
  const int nwg = (M_DIM / BM) * (N_DIM / BN);
  const int wg = (blockIdx.x & 7) * (nwg >> 3) + (blockIdx.x >> 3);
  const int bm = wg / (N_DIM / BN);
  const int bn = wg % (N_DIM / BN);

  // ---- reg-staging addressing: LINEAR global loads, SWIZZLED ds_write ----
  const signed char* aGl = A + ((size_t)(bm * BM + (t >> 3))) * K_DIM + (t & 7) * 16;
  const signed char* bGl = B + ((size_t)(bn * BN + (t >> 3))) * K_DIM + (t & 7) * 16;
  // LDS write offset: row*128 + (chunk ^ (row&7))*16
  const int wrOff = (t >> 3) * 128 + (((t & 7) ^ ((t >> 3) & 7)) * 16);

  v4i sA[4], sB[4];   // staging registers (one tile in flight)

#define GL_A(u, P) sA[u] = *(const v4i*)((P) + (size_t)((u) * 64) * K_DIM)
#define GL_B(u, P) sB[u] = *(const v4i*)((P) + (size_t)((u) * 64) * K_DIM)
#define WR_A(BUF) { _Pragma("unroll") for (int u = 0; u < 4; ++u) \
    *(v4i*)&As[BUF][u * 8192 + wrOff] = sA[u]; }
#define WR_B(BUF) { _Pragma("unroll") for (int u = 0; u < 4; ++u) \
    *(v4i*)&Bs[BUF][u * 8192 + wrOff] = sB[u]; }

  // ---- fragment read addressing (zero-conflict XOR layout) ----
  const int l7 = l15 & 7;
  const int soK0 = ((0 + l4) ^ l7) * 16;   // kstep 0 chunk
  const int soK1 = ((4 + l4) ^ l7) * 16;   // kstep 1 chunk
  const int aRd = (wm * 128 + l15) * BKB;
  const int bRd = (wn * 64 + l15) * BKB;

  v4i acc[8][4] = {};
  v4i bF[4][2], aF[2][2];

#define LOAD_B(buf) \
  { _Pragma("unroll") for (int nc = 0; nc < 4; ++nc) { \
      bF[nc][0] = *(const v4i*)&Bs[buf][bRd + nc * 2048 + soK0]; \
      bF[nc][1] = *(const v4i*)&Bs[buf][bRd + nc * 2048 + soK1]; } }

#define LOAD_A(buf, q) \
  aF[0][0] = *(const v4i*)&As[buf][aRd + (2*(q)) * 2048 + soK0]; \
  aF[0][1] = *(const v4i*)&As[buf][aRd + (2*(q)) * 2048 + soK1]; \
  aF[1][0] = *(const v4i*)&As[buf][aRd + (2*(q)+1) * 2048 + soK0]; \
  aF[1][1] = *(const v4i*)&As[buf][aRd + (2*(q)+1) * 2048 + soK1];

#define MFMA_Q(q) \
  { _Pragma("unroll") for (int nc = 0; nc < 4; ++nc) { \
      acc[2*(q)][nc]   = __builtin_amdgcn_mfma_i32_16x16x64_i8(aF[0][0], bF[nc][0], acc[2*(q)][nc], 0, 0, 0); \
      acc[2*(q)][nc]   = __builtin_amdgcn_mfma_i32_16x16x64_i8(aF[0][1], bF[nc][1], acc[2*(q)][nc], 0, 0, 0); \
      acc[2*(q)+1][nc] = __builtin_amdgcn_mfma_i32_16x16x64_i8(aF[1][0], bF[nc][0], acc[2*(q)+1][nc], 0, 0, 0); \
      acc[2*(q)+1][nc] = __builtin_amdgcn_mfma_i32_16x16x64_i8(aF[1][1], bF[nc][1], acc[2*(q)+1][nc], 0, 0, 0); } }

#define BAR __builtin_amdgcn_s_barrier()

  // One K-tile: 4 quarters in program order, no intra-tile barriers; single
  // lgkmcnt(0)+barrier at the buffer flip (verified champion schedule).
#define TILE_BODY(BUF, PA, PB) do { \
    LOAD_B(BUF); LOAD_A(BUF, 0); \
    GL_B(0, PB); GL_B(1, PB); \
    __builtin_amdgcn_s_setprio(1); MFMA_Q(0); __builtin_amdgcn_s_setprio(0); \
    LOAD_A(BUF, 1); \
    GL_B(2, PB); GL_B(3, PB); \
    __builtin_amdgcn_s_setprio(1); MFMA_Q(1); __builtin_amdgcn_s_setprio(0); \
    LOAD_A(BUF, 2); \
    GL_A(0, PA); GL_A(1, PA); GL_A(2, PA); GL_A(3, PA); \
    __builtin_amdgcn_s_setprio(1); MFMA_Q(2); __builtin_amdgcn_s_setprio(0); \
    WR_B(BUF^1); \
    LOAD_A(BUF, 3); \
    __builtin_amdgcn_s_setprio(1); MFMA_Q(3); __builtin_amdgcn_s_setprio(0); \
    WR_A(BUF^1); \
    asm volatile("s_waitcnt lgkmcnt(0)" ::: "memory"); \
    BAR; \
  } while (0)

  // Final tile: no staging, no flip drain/barrier (epilogue reads no LDS;
  // per-use waits cover the last MFMAs).
#define TILE_LAST(BUF) do { \
    LOAD_B(BUF); LOAD_A(BUF, 0); \
    __builtin_amdgcn_s_setprio(1); MFMA_Q(0); __builtin_amdgcn_s_setprio(0); \
    LOAD_A(BUF, 1); \
    __builtin_amdgcn_s_setprio(1); MFMA_Q(1); __builtin_amdgcn_s_setprio(0); \
    LOAD_A(BUF, 2); \
    __builtin_amdgcn_s_setprio(1); MFMA_Q(2); __builtin_amdgcn_s_setprio(0); \
    LOAD_A(BUF, 3); \
    __builtin_amdgcn_s_setprio(1); MFMA_Q(3); __builtin_amdgcn_s_setprio(0); \
  } while (0)

  // ---- prologue: load + write tile 0 ----
  GL_B(0, bGl); GL_B(1, bGl); GL_B(2, bGl); GL_B(3, bGl);
  GL_A(0, aGl); GL_A(1, aGl); GL_A(2, aGl); GL_A(3, aGl);
  asm volatile("s_waitcnt vmcnt(0)" ::: "memory");
  WR_B(0); WR_A(0);
  asm volatile("s_waitcnt lgkmcnt(0)" ::: "memory");
  BAR;
  __builtin_amdgcn_sched_barrier(0);

  // ---- main loop: 2 K-tiles per iteration, compile-time buffer selection ----
  const signed char* aGk = aGl;
  const signed char* bGk = bGl;
  for (int it = 0; it < NT / 2 - 1; ++it) {
    TILE_BODY(0, aGk + BKB,     bGk + BKB);       // tile 2it,   load 2it+1
    TILE_BODY(1, aGk + 2 * BKB, bGk + 2 * BKB);   // tile 2it+1, load 2it+2
    aGk += 2 * BKB; bGk += 2 * BKB;
  }
  TILE_BODY(0, aGk + BKB, bGk + BKB);             // tile 30, load 31
  TILE_LAST(1);                                   // tile 31, no staging

  // ---- epilogue: out = acc * (clamped_act_scale * alpha) + bias ----
  const float sA_ = fmaxf(act_scale_p[0], 1e-5f) * alpha_p[0];
  const int gn0 = bn * BN + wn * 64 + l15;
  const int gm0 = bm * BM + wm * 128 + l4 * 4;
#pragma unroll
  for (int nc = 0; nc < 4; ++nc) {
    const float bv = bias[gn0 + nc * 16];
#pragma unroll
    for (int mr = 0; mr < 8; ++mr) {
#pragma unroll
      for (int r = 0; r < 4; ++r) {
        const int gm = gm0 + mr * 16 + r;          // C/D: col=lane&15, row=(lane>>4)*4+reg
        out[(size_t)gm * N_DIM + gn0 + nc * 16] = (float)acc[mr][nc][r] * sA_ + bv;
      }
    }
  }
}

extern "C" void kernel_launch(void* const* d_in, const int* in_sizes, int n_in,
                              void* d_out, int out_size, void* d_ws, size_t ws_size,
                              hipStream_t stream) {
  const float* x      = (const float*)d_in[0];
  const int*   pw     = (const int*)d_in[1];
  const float* alpha  = (const float*)d_in[2];
  const float* act_sc = (const float*)d_in[3];
  const float* bias   = (const float*)d_in[4];
  float* out = (float*)d_out;

  signed char* x8 = (signed char*)d_ws;                          // 64 MiB
  signed char* w8 = (signed char*)d_ws + (size_t)M_DIM * K_DIM;  // 16 MiB

  prep_kernel<<<QBLK + PBLK, 256, 0, stream>>>(
      (const float4*)x, (int4*)x8, M_DIM * K_DIM / 16,
      (const int4*)pw, (int4*)w8, N_DIM * K_DIM / 16, act_sc);

  dim3 grid((M_DIM / BM) * (N_DIM / BN));   // 1024 blocks, 1-D for XCD swizzle
  bitlinear_gemm<<<grid, 512, 0, stream>>>(x8, w8, bias, alpha, act_sc, out);
}

// Round 12
// 360.547 us; speedup vs baseline: 1.4933x; 1.0065x over previous
//
#include <hip/hip_runtime.h>
#include <hip/hip_bf16.h>

typedef int v4i __attribute__((ext_vector_type(4)));

#define M_DIM 16384
#define N_DIM 4096
#define K_DIM 4096
#define BM 256
#define BN 256
#define BKB 128                 // K-bytes per tile
#define NT (K_DIM / BKB)        // 32 K-tiles

#define QBLK 2048               // quant-x blocks in fused prep
#define PBLK 512                // pack-w blocks in fused prep

// ---- fused pre-pass: grid-partitioned quant(x) || pack(w).
// r5: reciprocal-multiply (div was VALU-bound). r6: fused single launch.
// r9: 4 vectors/lane -> one int4 (16B) store.
__global__ void prep_kernel(const float4* __restrict__ x, int4* __restrict__ qx, int n16x,
                            const int4* __restrict__ w, int4* __restrict__ qw, int n16w,
                            const float* __restrict__ act_scale) {
  if (blockIdx.x < QBLK) {
    const float s = fmaxf(act_scale[0], 1e-5f);
    const float inv_s = 1.0f / s;
#define PKQ(v) (( (int)fminf(fmaxf(rintf((v).x * inv_s), -127.f), 127.f) & 0xff)        | \
               (((int)fminf(fmaxf(rintf((v).y * inv_s), -127.f), 127.f) & 0xff) << 8)  | \
               (((int)fminf(fmaxf(rintf((v).z * inv_s), -127.f), 127.f) & 0xff) << 16) | \
               (((int)fminf(fmaxf(rintf((v).w * inv_s), -127.f), 127.f) & 0xff) << 24))
    int i = blockIdx.x * blockDim.x + threadIdx.x;
    const int stride = QBLK * blockDim.x;
    for (; i < n16x; i += stride) {
      const float4* xp = x + (size_t)i * 4;
      float4 v0 = xp[0], v1 = xp[1], v2 = xp[2], v3 = xp[3];
      int4 o;
      o.x = PKQ(v0); o.y = PKQ(v1); o.z = PKQ(v2); o.w = PKQ(v3);
      qx[i] = o;
    }
  } else {
#define PKW(v) ((((v).x - 1) & 0xff) | ((((v).y - 1) & 0xff) << 8) | \
                ((((v).z - 1) & 0xff) << 16) | ((((v).w - 1) & 0xff) << 24))
    int i = (blockIdx.x - QBLK) * blockDim.x + threadIdx.x;
    const int stride = PBLK * blockDim.x;
    for (; i < n16w; i += stride) {
      const int4* wp = w + (size_t)i * 4;
      int4 v0 = wp[0], v1 = wp[1], v2 = wp[2], v3 = wp[3];
      int4 o;
      o.x = PKW(v0); o.y = PKW(v1); o.z = PKW(v2); o.w = PKW(v3);
      qw[i] = o;
    }
  }
}

// ---- i8 GEMM: r11 champion structure with TAIL-SHADOW restructure (r12).
// Change vs champion (order only): all 8 staging GLs issue at tile TOP
// (>=1000cyc slack to their implicit vmcnt waits, vs ~330 for A before);
// WR_B before MFMA_Q2, WR_A before MFMA_Q3 -> the 8 ds_writes/wave (~96cyc)
// hide under Q3's ~327cyc MFMA cluster, and the closing lgkmcnt(0)+barrier
// finds nothing in flight (drain collapses). Aliasing safe: reads hit BUF,
// writes hit BUF^1; pinned lgkm asm prevents store sinking. Rationale: r9's
// TILE_LAST (removing ONE tile's staging tail) gained far beyond dead-work
// arithmetic -> the vmcnt->ds_write->lgkm->barrier tail is substantially
// EXPOSED each tile; this buries it every tile.
// Ledger (GEMM us): champion 272 | ladder 305 | DMA 312-315 | 128^2 390 |
// 32x32 297 (conflicts) | A-from-L2 584 | 16-wave 444.
__global__ __launch_bounds__(512, 2) void bitlinear_gemm(
    const signed char* __restrict__ A,   // [M][K] i8
    const signed char* __restrict__ B,   // [N][K] i8
    const float* __restrict__ bias,
    const float* __restrict__ alpha_p,
    const float* __restrict__ act_scale_p,
    float* __restrict__ out) {
  __shared__ __align__(16) signed char As[2][BM * BKB];   // 2 x 32 KiB
  __shared__ __align__(16) signed char Bs[2][BN * BKB];   // 2 x 32 KiB

  const int t = threadIdx.x;
  const int lane = t & 63, wid = t >> 6;
  const int wm = wid >> 2, wn = wid & 3;       // 2M x 4N waves
  const int l15 = lane & 15, l4 = lane >> 4;

  // XCD-aware bijective swizzle (nwg=1024, divisible by 8)
  const int nwg = (M_DIM / BM) * (N_DIM / BN);
  const int wg = (blockIdx.x & 7) * (nwg >> 3) + (blockIdx.x >> 3);
  const int bm = wg / (N_DIM / BN);
  const int bn = wg % (N_DIM / BN);

  // ---- reg-staging addressing: LINEAR global loads, SWIZZLED ds_write ----
  const signed char* aGl = A + ((size_t)(bm * BM + (t >> 3))) * K_DIM + (t & 7) * 16;
  const signed char* bGl = B + ((size_t)(bn * BN + (t >> 3))) * K_DIM + (t & 7) * 16;
  // LDS write offset: row*128 + (chunk ^ (row&7))*16
  const int wrOff = (t >> 3) * 128 + (((t & 7) ^ ((t >> 3) & 7)) * 16);

  v4i sA[4], sB[4];   // staging registers (one tile in flight)

#define GL_A(u, P) sA[u] = *(const v4i*)((P) + (size_t)((u) * 64) * K_DIM)
#define GL_B(u, P) sB[u] = *(const v4i*)((P) + (size_t)((u) * 64) * K_DIM)
#define WR_A(BUF) { _Pragma("unroll") for (int u = 0; u < 4; ++u) \
    *(v4i*)&As[BUF][u * 8192 + wrOff] = sA[u]; }
#define WR_B(BUF) { _Pragma("unroll") for (int u = 0; u < 4; ++u) \
    *(v4i*)&Bs[BUF][u * 8192 + wrOff] = sB[u]; }

  // ---- fragment read addressing (zero-conflict XOR layout) ----
  const int l7 = l15 & 7;
  const int soK0 = ((0 + l4) ^ l7) * 16;   // kstep 0 chunk
  const int soK1 = ((4 + l4) ^ l7) * 16;   // kstep 1 chunk
  const int aRd = (wm * 128 + l15) * BKB;
  const int bRd = (wn * 64 + l15) * BKB;

  v4i acc[8][4] = {};
  v4i bF[4][2], aF[2][2];

#define LOAD_B(buf) \
  { _Pragma("unroll") for (int nc = 0; nc < 4; ++nc) { \
      bF[nc][0] = *(const v4i*)&Bs[buf][bRd + nc * 2048 + soK0]; \
      bF[nc][1] = *(const v4i*)&Bs[buf][bRd + nc * 2048 + soK1]; } }

#define LOAD_A(buf, q) \
  aF[0][0] = *(const v4i*)&As[buf][aRd + (2*(q)) * 2048 + soK0]; \
  aF[0][1] = *(const v4i*)&As[buf][aRd + (2*(q)) * 2048 + soK1]; \
  aF[1][0] = *(const v4i*)&As[buf][aRd + (2*(q)+1) * 2048 + soK0]; \
  aF[1][1] = *(const v4i*)&As[buf][aRd + (2*(q)+1) * 2048 + soK1];

#define MFMA_Q(q) \
  { _Pragma("unroll") for (int nc = 0; nc < 4; ++nc) { \
      acc[2*(q)][nc]   = __builtin_amdgcn_mfma_i32_16x16x64_i8(aF[0][0], bF[nc][0], acc[2*(q)][nc], 0, 0, 0); \
      acc[2*(q)][nc]   = __builtin_amdgcn_mfma_i32_16x16x64_i8(aF[0][1], bF[nc][1], acc[2*(q)][nc], 0, 0, 0); \
      acc[2*(q)+1][nc] = __builtin_amdgcn_mfma_i32_16x16x64_i8(aF[1][0], bF[nc][0], acc[2*(q)+1][nc], 0, 0, 0); \
      acc[2*(q)+1][nc] = __builtin_amdgcn_mfma_i32_16x16x64_i8(aF[1][1], bF[nc][1], acc[2*(q)+1][nc], 0, 0, 0); } }

#define BAR __builtin_amdgcn_s_barrier()

  // One K-tile, tail-shadow order: all GLs at top; WR_B pre-Q2, WR_A pre-Q3
  // (writes hide under MFMA); single lgkmcnt(0)+barrier at the flip with an
  // empty LDS queue.
#define TILE_BODY(BUF, PA, PB) do { \
    LOAD_B(BUF); LOAD_A(BUF, 0); \
    GL_B(0, PB); GL_B(1, PB); GL_B(2, PB); GL_B(3, PB); \
    GL_A(0, PA); GL_A(1, PA); GL_A(2, PA); GL_A(3, PA); \
    __builtin_amdgcn_s_setprio(1); MFMA_Q(0); __builtin_amdgcn_s_setprio(0); \
    LOAD_A(BUF, 1); \
    __builtin_amdgcn_s_setprio(1); MFMA_Q(1); __builtin_amdgcn_s_setprio(0); \
    LOAD_A(BUF, 2); \
    WR_B(BUF^1); \
    __builtin_amdgcn_s_setprio(1); MFMA_Q(2); __builtin_amdgcn_s_setprio(0); \
    LOAD_A(BUF, 3); \
    WR_A(BUF^1); \
    __builtin_amdgcn_s_setprio(1); MFMA_Q(3); __builtin_amdgcn_s_setprio(0); \
    asm volatile("s_waitcnt lgkmcnt(0)" ::: "memory"); \
    BAR; \
  } while (0)

  // Final tile: no staging, no flip drain/barrier (r9 trim).
#define TILE_LAST(BUF) do { \
    LOAD_B(BUF); LOAD_A(BUF, 0); \
    __builtin_amdgcn_s_setprio(1); MFMA_Q(0); __builtin_amdgcn_s_setprio(0); \
    LOAD_A(BUF, 1); \
    __builtin_amdgcn_s_setprio(1); MFMA_Q(1); __builtin_amdgcn_s_setprio(0); \
    LOAD_A(BUF, 2); \
    __builtin_amdgcn_s_setprio(1); MFMA_Q(2); __builtin_amdgcn_s_setprio(0); \
    LOAD_A(BUF, 3); \
    __builtin_amdgcn_s_setprio(1); MFMA_Q(3); __builtin_amdgcn_s_setprio(0); \
  } while (0)

  // ---- prologue: load + write tile 0 ----
  GL_B(0, bGl); GL_B(1, bGl); GL_B(2, bGl); GL_B(3, bGl);
  GL_A(0, aGl); GL_A(1, aGl); GL_A(2, aGl); GL_A(3, aGl);
  asm volatile("s_waitcnt vmcnt(0)" ::: "memory");
  WR_B(0); WR_A(0);
  asm volatile("s_waitcnt lgkmcnt(0)" ::: "memory");
  BAR;
  __builtin_amdgcn_sched_barrier(0);

  // ---- main loop: 2 K-tiles per iteration, compile-time buffer selection ----
  const signed char* aGk = aGl;
  const signed char* bGk = bGl;
  for (int it = 0; it < NT / 2 - 1; ++it) {
    TILE_BODY(0, aGk + BKB,     bGk + BKB);       // tile 2it,   load 2it+1
    TILE_BODY(1, aGk + 2 * BKB, bGk + 2 * BKB);   // tile 2it+1, load 2it+2
    aGk += 2 * BKB; bGk += 2 * BKB;
  }
  TILE_BODY(0, aGk + BKB, bGk + BKB);             // tile 30, load 31
  TILE_LAST(1);                                   // tile 31, no staging

  // ---- epilogue: out = acc * (clamped_act_scale * alpha) + bias ----
  const float sA_ = fmaxf(act_scale_p[0], 1e-5f) * alpha_p[0];
  const int gn0 = bn * BN + wn * 64 + l15;
  const int gm0 = bm * BM + wm * 128 + l4 * 4;
#pragma unroll
  for (int nc = 0; nc < 4; ++nc) {
    const float bv = bias[gn0 + nc * 16];
#pragma unroll
    for (int mr = 0; mr < 8; ++mr) {
#pragma unroll
      for (int r = 0; r < 4; ++r) {
        const int gm = gm0 + mr * 16 + r;          // C/D: col=lane&15, row=(lane>>4)*4+reg
        out[(size_t)gm * N_DIM + gn0 + nc * 16] = (float)acc[mr][nc][r] * sA_ + bv;
      }
    }
  }
}

extern "C" void kernel_launch(void* const* d_in, const int* in_sizes, int n_in,
                              void* d_out, int out_size, void* d_ws, size_t ws_size,
                              hipStream_t stream) {
  const float* x      = (const float*)d_in[0];
  const int*   pw     = (const int*)d_in[1];
  const float* alpha  = (const float*)d_in[2];
  const float* act_sc = (const float*)d_in[3];
  const float* bias   = (const float*)d_in[4];
  float* out = (float*)d_out;

  signed char* x8 = (signed char*)d_ws;                          // 64 MiB
  signed char* w8 = (signed char*)d_ws + (size_t)M_DIM * K_DIM;  // 16 MiB

  prep_kernel<<<QBLK + PBLK, 256, 0, stream>>>(
      (const float4*)x, (int4*)x8, M_DIM * K_DIM / 16,
      (const int4*)pw, (int4*)w8, N_DIM * K_DIM / 16, act_sc);

  dim3 grid((M_DIM / BM) * (N_DIM / BN));   // 1024 blocks, 1-D for XCD swizzle
  bitlinear_gemm<<<grid, 512, 0, stream>>>(x8, w8, bias, alpha, act_sc, out);
}